// Round 17
// baseline (214.198 us; speedup 1.0000x reference)
//
#include <hip/hip_runtime.h>
#include <cstdint>
#include <cstddef>

// Problem constants: B=4,S=2048,D=1024,E=32,H=128,K=2
#define NTOK 8192
#define DIM  1024
#define NEXP 32
#define NH   128
#define TT   32               // tokens per FFN tile
#define NSLOT 32              // tile slots per expert (32*32 = 1024 = LCAP)
#define BK   128              // K-chunk for ffn phase A
#define RT   16               // tokens per router block (split for 2 blocks/CU)
#define LCAP 1024             // per-expert list capacity (mean 512, sigma~22)
#define NRB  (NTOK / RT)      // 512 router blocks
#define NTRB 2048             // transpose blocks

typedef __attribute__((ext_vector_type(8))) short short8;
typedef __attribute__((ext_vector_type(4))) float float4_;

static __device__ __forceinline__ unsigned short f2bf(float f) {
  unsigned u = __float_as_uint(f);
  return (unsigned short)((u + 0x7fffu + ((u >> 16) & 1u)) >> 16);
}
static __device__ __forceinline__ float bf2f(unsigned short h) {
  return __uint_as_float(((unsigned)h) << 16);
}
// async global->LDS, 16 B/lane; LDS dest = uniform base + lane*16 (HW rule).
static __device__ __forceinline__ void gload_lds16(const unsigned short* g,
                                                   unsigned short* l) {
  __builtin_amdgcn_global_load_lds(
      (const __attribute__((address_space(1))) unsigned int*)(const void*)g,
      (__attribute__((address_space(3))) unsigned int*)(void*)l, 16, 0, 0);
}

// ---------------- Fused prep + router (RT=16: 512 blocks, 2/CU) -------------
// bid < NRB: router over 16 tokens (fp32 logits, exact top-2) + fused x->bf16.
//   Same numeric structure as R13 (per-logit d-order identical); per-thread
//   tile 4 tok x 2 exp over a 16-d split-K quarter. Two co-resident blocks
//   per CU overlap each other's barrier stalls (R14's proven mechanism,
//   without its extra-kernel overhead).
// bid >= NRB: 64x64 transpose tiles (2048 blocks).
__global__ __launch_bounds__(256) void prep_router_kernel(
    const float* __restrict__ x, const float* __restrict__ w_sel,
    const float* __restrict__ w_keys, const float* __restrict__ w_values,
    unsigned short* __restrict__ xbf, unsigned short* __restrict__ wk_t,
    unsigned short* __restrict__ wv_t,
    int* __restrict__ counts, unsigned* __restrict__ list)
{
  __shared__ __align__(16) char smem[16640];
  const int bid = blockIdx.x;
  const int tid = threadIdx.x;

  if (bid >= NRB) {
    // ---- 64x64 transpose tile: src fp32 [R][C] -> dst bf16 [C][R] ----------
    float (*tile)[65] = (float (*)[65])smem;
    const int lb = bid - NRB;
    const float* src; unsigned short* dst; int R, C, e, t, tpc;
    if (lb < 1024) { src = w_keys;   dst = wk_t; R = DIM; C = NH;  e = lb >> 5;          t = lb & 31; tpc = 2; }
    else           { src = w_values; dst = wv_t; R = NH;  C = DIM; e = (lb - 1024) >> 5; t = (lb - 1024) & 31; tpc = 16; }
    const int r0 = (t / tpc) * 64;
    const int c0 = (t % tpc) * 64;
    const float* s = src + (size_t)e * R * C;
    unsigned short* d = dst + (size_t)e * R * C;

    const int i  = tid >> 2;          // 0..63 source row
    const int j0 = (tid & 3) * 16;    // 0,16,32,48 source col base
    #pragma unroll
    for (int k4 = 0; k4 < 4; ++k4) {
      float4 v = *(const float4*)(s + (size_t)(r0 + i) * C + c0 + j0 + k4 * 4);
      tile[i][j0 + k4 * 4 + 0] = v.x;
      tile[i][j0 + k4 * 4 + 1] = v.y;
      tile[i][j0 + k4 * 4 + 2] = v.z;
      tile[i][j0 + k4 * 4 + 3] = v.w;
    }
    __syncthreads();
    unsigned pk[8];
    #pragma unroll
    for (int k = 0; k < 8; ++k) {
      unsigned lo = f2bf(tile[j0 + 2 * k][i]);
      unsigned hi = f2bf(tile[j0 + 2 * k + 1][i]);
      pk[k] = lo | (hi << 16);
    }
    uint4 u0; u0.x = pk[0]; u0.y = pk[1]; u0.z = pk[2]; u0.w = pk[3];
    uint4 u1; u1.x = pk[4]; u1.y = pk[5]; u1.z = pk[6]; u1.w = pk[7];
    unsigned short* dp = d + (size_t)(c0 + i) * R + r0 + j0;
    *(uint4*)(dp)     = u0;
    *(uint4*)(dp + 8) = u1;
    return;
  }

  // ---- router block ---------------------------------------------------------
  // xs_t [d=64][tok 16+4], XOR-4block swizzled (writes 2-way-free, reads bcast)
  // ws_t [d=64][e 32+4],  R13's proven swizzle
  // S    [tok=16][e 32+1]
  // red  [wave][tok16][e 33] aliases staging (barrier-separated)
  float (*xs_t)[20] = (float (*)[20])smem;                     // 5120 B
  float (*ws_t)[36] = (float (*)[36])(smem + 5120);            // 9216 B
  float (*S)[33]    = (float (*)[33])(smem + 5120 + 9216);     // 2112 B
  float (*red)[16][33] = (float (*)[16][33])smem;              // 8448 B alias

  const int tok0 = bid * RT;
  const int wv   = tid >> 6;           // wave: owns d-quarter [wv*16, wv*16+16)
  const int lane = tid & 63;

  // staging roles
  const int tr2  = tid >> 4;           // x staging: token 0..15
  const int d16c = (tid & 15) * 4;     // x staging: 4-float column base
  const int tr   = tid >> 3;           // w staging: expert 0..31
  const int i8   = tid & 7;
  const int d8   = i8 * 8;
  const int swzW = i8 << 2;            // w write swizzle key (R13)

  // compute roles
  const int tg4  = (lane & 3) * 4;     // token group base (4 tokens)
  const int eg2  = (lane >> 2) * 2;    // expert pair base (2 experts)
  const int dlo  = wv * 16;

  // x-column swizzle key: XOR of 4-blocks, bijective & alignment-preserving
  const int sxw  = ((((d16c) >> 2) ^ ((d16c) >> 4)) & 3) << 2;

  float acc[8];
  #pragma unroll
  for (int k = 0; k < 8; ++k) acc[k] = 0.f;

  // prologue: load chunk 0 into regs
  float4 a0, b0, b1;
  {
    a0 = *(const float4*)(x + (size_t)(tok0 + tr2) * DIM + d16c);
    const float* wp = w_sel + (size_t)tr * DIM + d8;
    b0 = *(const float4*)(wp);
    b1 = *(const float4*)(wp + 4);
  }

  for (int c = 0; c < 16; ++c) {
    const int dc = c * 64;

    // write current chunk regs -> LDS (x and w transposed, swizzled cols)
    // + fused xbf bf16 store
    {
      const int colx = tr2 ^ sxw;
      xs_t[d16c + 0][colx] = a0.x; xs_t[d16c + 1][colx] = a0.y;
      xs_t[d16c + 2][colx] = a0.z; xs_t[d16c + 3][colx] = a0.w;
      const int colw = tr ^ swzW;
      ws_t[d8 + 0][colw] = b0.x; ws_t[d8 + 1][colw] = b0.y;
      ws_t[d8 + 2][colw] = b0.z; ws_t[d8 + 3][colw] = b0.w;
      ws_t[d8 + 4][colw] = b1.x; ws_t[d8 + 5][colw] = b1.y;
      ws_t[d8 + 6][colw] = b1.z; ws_t[d8 + 7][colw] = b1.w;
      uint2 u;
      u.x = (unsigned)f2bf(a0.x) | ((unsigned)f2bf(a0.y) << 16);
      u.y = (unsigned)f2bf(a0.z) | ((unsigned)f2bf(a0.w) << 16);
      *(uint2*)(xbf + (size_t)(tok0 + tr2) * DIM + dc + d16c) = u;
    }
    __syncthreads();

    // prefetch chunk c+1 into regs; drains under the FMA block below
    if (c < 15) {
      a0 = *(const float4*)(x + (size_t)(tok0 + tr2) * DIM + dc + 64 + d16c);
      const float* wp = w_sel + (size_t)tr * DIM + dc + 64 + d8;
      b0 = *(const float4*)(wp);
      b1 = *(const float4*)(wp + 4);
    }

    // compute: 16 d x (4 tok x 2 exp); both reads broadcast, conflict-free
    #pragma unroll
    for (int dd = 0; dd < 16; ++dd) {
      const int d  = dlo + dd;
      const int sx = ((((d) >> 2) ^ ((d) >> 4)) & 3) << 2;
      const int sw = (d >> 3) << 2;
      float4 xv = *(const float4*)&xs_t[d][tg4 ^ sx];
      float2 w2 = *(const float2*)&ws_t[d][eg2 ^ sw];
      acc[0] = fmaf(w2.x, xv.x, acc[0]);
      acc[1] = fmaf(w2.x, xv.y, acc[1]);
      acc[2] = fmaf(w2.x, xv.z, acc[2]);
      acc[3] = fmaf(w2.x, xv.w, acc[3]);
      acc[4] = fmaf(w2.y, xv.x, acc[4]);
      acc[5] = fmaf(w2.y, xv.y, acc[5]);
      acc[6] = fmaf(w2.y, xv.z, acc[6]);
      acc[7] = fmaf(w2.y, xv.w, acc[7]);
    }
    __syncthreads();   // protect LDS before next chunk's writes
  }

  // cross-wave K reduction: red aliases staging (all staging reads done)
  #pragma unroll
  for (int k = 0; k < 2; ++k)
    #pragma unroll
    for (int j = 0; j < 4; ++j)
      red[wv][tg4 + j][eg2 + k] = acc[k * 4 + j];
  __syncthreads();

  {
    #pragma unroll
    for (int h = 0; h < 2; ++h) {
      const int o   = h * 256 + tid;
      const int tok = o & 15, ee = o >> 4;
      S[tok][ee] = red[0][tok][ee] + red[1][tok][ee]
                 + red[2][tok][ee] + red[3][tok][ee];
    }
  }
  __syncthreads();

  if (tid < RT) {
    const int t = tid;
    float m1 = -1e30f, m2 = -1e30f;
    int i1 = 0, i2 = 0;
    for (int ee = 0; ee < NEXP; ++ee) {
      float v = S[t][ee];
      if (v > m1)      { m2 = m1; i2 = i1; m1 = v; i1 = ee; }
      else if (v > m2) { m2 = v; i2 = ee; }
    }
    const int token = tok0 + t;
    float g1 = 1.f / (1.f + __expf(-m1));
    float g2 = 1.f / (1.f + __expf(-m2));
    unsigned e1 = ((unsigned)f2bf(g1) << 16) | ((unsigned)token << 1);
    unsigned e2 = ((unsigned)f2bf(g2) << 16) | ((unsigned)token << 1) | 1u;
    int p1 = atomicAdd(&counts[i1], 1);
    if (p1 < LCAP) list[i1 * LCAP + p1] = e1;
    int p2 = atomicAdd(&counts[i2], 1);
    if (p2 < LCAP) list[i2 * LCAP + p2] = e2;
  }
}

// ---------------- Expert FFN: TT=32 tiles, LDS-bounced stores (R13) ---------
__global__ __launch_bounds__(256, 4) void ffn_kernel(
    const unsigned short* __restrict__ xbf,
    const unsigned short* __restrict__ wk_t,   // bf16 [E][H][D]
    const unsigned short* __restrict__ wv_t,   // bf16 [E][D][H]
    float* __restrict__ out,                   // atomic mode
    unsigned short* __restrict__ cont,         // cont mode [2][NTOK][DIM] bf16
    const int* __restrict__ counts, const unsigned* __restrict__ list,
    int use_cont)
{
  const int bid = blockIdx.x;
  const int e   = bid & 31;                    // bid%8 == e%8 -> expert stays on one XCD
  const int cnt = min(counts[e], LCAP);
  const int t0  = (bid >> 5) * TT;
  if (t0 >= cnt) return;

  // xsf: A-fragments, frag (mt*4+kk)*512 + lane*8 (lane-contiguous for gload_lds)
  // st : store-bounce [32 rows][256 cols + pad], unioned with xsf (disjoint phases)
  __shared__ __align__(16) unsigned short uni[8448];   // max(2*4096, 32*264) shorts
  __shared__ unsigned short ss[TT][NH + 8];
  __shared__ int   toks[TT];
  __shared__ float gates[TT];
  unsigned short (*xsf)[4096] = (unsigned short (*)[4096])uni;
  unsigned short (*st)[264]   = (unsigned short (*)[264])uni;

  const int tid  = threadIdx.x;
  const int wave = tid >> 6;
  const int lane = tid & 63;
  const int quad = lane >> 4;
  const int l16  = lane & 15;

  const unsigned short* wkb = wk_t + (size_t)e * NH * DIM;
  const unsigned short* wvb = wv_t + (size_t)e * DIM * NH;
  const int n_tok = min(TT, cnt - t0);

  if (tid < TT) {
    int valid = tid < n_tok;
    unsigned en = valid ? list[e * LCAP + t0 + tid] : 0u;
    toks[tid]  = valid ? (int)(en & 0xffffu) : -1;
    gates[tid] = valid ? bf2f((unsigned short)(en >> 16)) : 0.f;
  }
  __syncthreads();

  // staging: waves {0,1} stage rows 0..15 (kk {0,1}/{2,3}), waves {2,3} rows 16..31
  const int smt  = wave >> 1;
  const int skk0 = (wave & 1) * 2;
  {
    int sl   = toks[smt * 16 + l16];
    int gtok = (sl < 0) ? 0 : (sl >> 1);
    const unsigned short* gsrc = xbf + (size_t)gtok * DIM + quad * 8;

    #pragma unroll
    for (int i2 = 0; i2 < 2; ++i2)
      gload_lds16(gsrc + (skk0 + i2) * 32, &xsf[0][(smt * 4 + skk0 + i2) * 512]);
    __syncthreads();

    // ---- Phase A: S = relu(X @ Wk) * gate  (M=32, N=128, K=1024)
    float4_ acc[2][2];
    #pragma unroll
    for (int mt = 0; mt < 2; ++mt)
      #pragma unroll
      for (int nt = 0; nt < 2; ++nt) acc[mt][nt] = (float4_){0.f, 0.f, 0.f, 0.f};

    for (int ci = 0; ci < 8; ++ci) {
      const int dc = ci * BK;
      if (ci < 7) {
        const int nb = (ci + 1) & 1;
        #pragma unroll
        for (int i2 = 0; i2 < 2; ++i2)
          gload_lds16(gsrc + dc + BK + (skk0 + i2) * 32,
                      &xsf[nb][(smt * 4 + skk0 + i2) * 512]);
      }
      short8 b[4][2];
      #pragma unroll
      for (int kk = 0; kk < 4; ++kk)
        #pragma unroll
        for (int nt = 0; nt < 2; ++nt)
          b[kk][nt] = *(const short8*)(wkb +
              (size_t)(wave * 32 + nt * 16 + l16) * DIM + dc + kk * 32 + quad * 8);

      const unsigned short* xb = &xsf[ci & 1][0];
      #pragma unroll
      for (int kk = 0; kk < 4; ++kk) {
        #pragma unroll
        for (int mt = 0; mt < 2; ++mt) {
          short8 a = *(const short8*)(xb + (mt * 4 + kk) * 512 + lane * 8);
          #pragma unroll
          for (int nt = 0; nt < 2; ++nt)
            acc[mt][nt] = __builtin_amdgcn_mfma_f32_16x16x32_bf16(a, b[kk][nt], acc[mt][nt], 0, 0, 0);
        }
      }
      __syncthreads();   // drains prefetch + protects buf reuse
    }

    // epilogue A: relu * gate -> bf16 scores
    #pragma unroll
    for (int mt = 0; mt < 2; ++mt)
      #pragma unroll
      for (int nt = 0; nt < 2; ++nt)
        #pragma unroll
        for (int r = 0; r < 4; ++r) {
          int row = mt * 16 + quad * 4 + r;
          float v = fmaxf(acc[mt][nt][r], 0.f) * gates[row];
          ss[row][wave * 32 + nt * 16 + l16] = f2bf(v);
        }
  }
  __syncthreads();       // xsf dead from here on -> st may alias it

  // ---- Phase B: O = S @ Wv  (M=32, N=1024, K=128)
  #pragma unroll 1
  for (int nc = 0; nc < 4; ++nc) {
    const int colbase = wave * 256 + nc * 64;
    float4_ o[2][4];
    #pragma unroll
    for (int mt = 0; mt < 2; ++mt)
      #pragma unroll
      for (int nt = 0; nt < 4; ++nt) o[mt][nt] = (float4_){0.f, 0.f, 0.f, 0.f};

    #pragma unroll
    for (int kk = 0; kk < 4; ++kk) {
      short8 bk[4];
      #pragma unroll
      for (int nt = 0; nt < 4; ++nt)
        bk[nt] = *(const short8*)(wvb +
            (size_t)(colbase + nt * 16 + l16) * NH + kk * 32 + quad * 8);
      short8 a0 = *(const short8*)&ss[l16][kk * 32 + quad * 8];
      short8 a1 = *(const short8*)&ss[16 + l16][kk * 32 + quad * 8];
      #pragma unroll
      for (int nt = 0; nt < 4; ++nt) {
        o[0][nt] = __builtin_amdgcn_mfma_f32_16x16x32_bf16(a0, bk[nt], o[0][nt], 0, 0, 0);
        o[1][nt] = __builtin_amdgcn_mfma_f32_16x16x32_bf16(a1, bk[nt], o[1][nt], 0, 0, 0);
      }
    }

    if (use_cont) {
      // bounce through LDS, then full 128B row-segment stores
      #pragma unroll
      for (int mt = 0; mt < 2; ++mt)
        #pragma unroll
        for (int nt = 0; nt < 4; ++nt)
          #pragma unroll
          for (int r = 0; r < 4; ++r)
            st[mt * 16 + quad * 4 + r][wave * 64 + nt * 16 + l16] = f2bf(o[mt][nt][r]);
      __syncthreads();
      #pragma unroll
      for (int q = 0; q < 4; ++q) {
        int idx = q * 256 + tid;
        int row = idx >> 5, seg = idx & 31;
        if (row < n_tok) {
          int sl2 = toks[row];
          size_t base = ((size_t)((sl2 & 1) * NTOK + (sl2 >> 1))) * DIM
                        + (seg >> 3) * 256 + nc * 64 + (seg & 7) * 8;
          *(short8*)&cont[base] = *(const short8*)&st[row][seg * 8];
        }
      }
      __syncthreads();   // st reused next nc
    } else {
      #pragma unroll
      for (int mt = 0; mt < 2; ++mt)
        #pragma unroll
        for (int r = 0; r < 4; ++r) {
          int row = mt * 16 + quad * 4 + r;
          if (row < n_tok) {
            size_t base = (size_t)(toks[row] >> 1) * DIM + colbase;
            #pragma unroll
            for (int nt = 0; nt < 4; ++nt)
              unsafeAtomicAdd(&out[base + nt * 16 + l16], o[mt][nt][r]);
          }
        }
    }
  }
}

// ---------------- Combine: out = cont[0] + cont[1] (bf16 -> f32) -----------
__global__ __launch_bounds__(256) void combine_kernel(
    const unsigned short* __restrict__ cont, float* __restrict__ out)
{
  size_t i = ((size_t)blockIdx.x * 256 + threadIdx.x) * 8;
  uint4 a = *(const uint4*)(cont + i);
  uint4 b = *(const uint4*)(cont + (size_t)NTOK * DIM + i);
  float4 r0, r1;
  r0.x = bf2f((unsigned short)(a.x & 0xffff)) + bf2f((unsigned short)(b.x & 0xffff));
  r0.y = bf2f((unsigned short)(a.x >> 16))    + bf2f((unsigned short)(b.x >> 16));
  r0.z = bf2f((unsigned short)(a.y & 0xffff)) + bf2f((unsigned short)(b.y & 0xffff));
  r0.w = bf2f((unsigned short)(a.y >> 16))    + bf2f((unsigned short)(b.y >> 16));
  r1.x = bf2f((unsigned short)(a.z & 0xffff)) + bf2f((unsigned short)(b.z & 0xffff));
  r1.y = bf2f((unsigned short)(a.z >> 16))    + bf2f((unsigned short)(b.z >> 16));
  r1.z = bf2f((unsigned short)(a.w & 0xffff)) + bf2f((unsigned short)(b.w & 0xffff));
  r1.w = bf2f((unsigned short)(a.w >> 16))    + bf2f((unsigned short)(b.w >> 16));
  *(float4*)(out + i) = r0;
  *(float4*)(out + i + 4) = r1;
}

extern "C" void kernel_launch(void* const* d_in, const int* in_sizes, int n_in,
                              void* d_out, int out_size, void* d_ws, size_t ws_size,
                              hipStream_t stream) {
  (void)in_sizes; (void)n_in;
  const float* x        = (const float*)d_in[0];
  const float* w_sel    = (const float*)d_in[1];
  const float* w_keys   = (const float*)d_in[2];
  const float* w_values = (const float*)d_in[3];
  float* out = (float*)d_out;

  // workspace layout
  char* ws = (char*)d_ws;
  size_t off = 0;
  int*            counts = (int*)(ws + off);            off += 4096;
  unsigned*       list   = (unsigned*)(ws + off);       off += (size_t)NEXP * LCAP * 4;      // 128 KB
  unsigned short* wk_t   = (unsigned short*)(ws + off); off += (size_t)NEXP * NH * DIM * 2;  // 8 MB
  unsigned short* wv_t   = (unsigned short*)(ws + off); off += (size_t)NEXP * NH * DIM * 2;  // 8 MB
  unsigned short* xbf    = (unsigned short*)(ws + off); off += (size_t)NTOK * DIM * 2;       // 16 MB
  unsigned short* cont   = (unsigned short*)(ws + off);
  size_t need_full = off + (size_t)2 * NTOK * DIM * 2;  // + 32 MB
  const int use_cont = (ws_size >= need_full) ? 1 : 0;

  hipMemsetAsync(counts, 0, NEXP * sizeof(int), stream);

  prep_router_kernel<<<NRB + NTRB, 256, 0, stream>>>(x, w_sel, w_keys, w_values,
                                                     xbf, wk_t, wv_t, counts, list);

  if (!use_cont)
    hipMemsetAsync(out, 0, (size_t)out_size * sizeof(float), stream);

  ffn_kernel<<<NEXP * NSLOT, 256, 0, stream>>>(xbf, wk_t, wv_t, out, cont,
                                               counts, list, use_cont);

  if (use_cont)
    combine_kernel<<<NTOK * DIM / (256 * 8), 256, 0, stream>>>(cont, out);
}

// Round 18
// 211.727 us; speedup vs baseline: 1.0117x; 1.0117x over previous
//
#include <hip/hip_runtime.h>
#include <cstdint>
#include <cstddef>

// Problem constants: B=4,S=2048,D=1024,E=32,H=128,K=2
#define NTOK 8192
#define DIM  1024
#define NEXP 32
#define NH   128
#define TT   32               // tokens per FFN tile
#define NSLOT 32              // tile slots per expert (32*32 = 1024 = LCAP)
#define BK   128              // K-chunk for ffn phase A
#define RT   32               // tokens per router block
#define LCAP 1024             // per-expert list capacity (mean 512, sigma~22)
#define NRB  (NTOK / RT)      // 256 router blocks

typedef __attribute__((ext_vector_type(8))) short short8;
typedef __attribute__((ext_vector_type(4))) float float4_;

static __device__ __forceinline__ unsigned short f2bf(float f) {
  unsigned u = __float_as_uint(f);
  return (unsigned short)((u + 0x7fffu + ((u >> 16) & 1u)) >> 16);
}
static __device__ __forceinline__ float bf2f(unsigned short h) {
  return __uint_as_float(((unsigned)h) << 16);
}
// async global->LDS, 16 B/lane; LDS dest = uniform base + lane*16 (HW rule).
static __device__ __forceinline__ void gload_lds16(const unsigned short* g,
                                                   unsigned short* l) {
  __builtin_amdgcn_global_load_lds(
      (const __attribute__((address_space(1))) unsigned int*)(const void*)g,
      (__attribute__((address_space(3))) unsigned int*)(void*)l, 16, 0, 0);
}

// ---------------- Fused prep + router (best-measured configuration) ---------
// bid < NRB: router over 32 tokens (fp32 logits, exact top-2) + fused x->bf16.
//   Thread = 4 tok x 4 exp over a 16-d split-K quarter; XOR-swizzled staging;
//   reg-prefetch double buffer; cross-wave K-reduce via aliased LDS.
// bid >= NRB: 64x64 transpose tiles (2048 blocks).
__global__ __launch_bounds__(256) void prep_router_kernel(
    const float* __restrict__ x, const float* __restrict__ w_sel,
    const float* __restrict__ w_keys, const float* __restrict__ w_values,
    unsigned short* __restrict__ xbf, unsigned short* __restrict__ wk_t,
    unsigned short* __restrict__ wv_t,
    int* __restrict__ counts, unsigned* __restrict__ list)
{
  __shared__ __align__(16) char smem[22656];
  const int bid = blockIdx.x;
  const int tid = threadIdx.x;

  if (bid >= NRB) {
    // ---- 64x64 transpose tile: src fp32 [R][C] -> dst bf16 [C][R] ----------
    float (*tile)[65] = (float (*)[65])smem;
    const int lb = bid - NRB;
    const float* src; unsigned short* dst; int R, C, e, t, tpc;
    if (lb < 1024) { src = w_keys;   dst = wk_t; R = DIM; C = NH;  e = lb >> 5;          t = lb & 31; tpc = 2; }
    else           { src = w_values; dst = wv_t; R = NH;  C = DIM; e = (lb - 1024) >> 5; t = (lb - 1024) & 31; tpc = 16; }
    const int r0 = (t / tpc) * 64;
    const int c0 = (t % tpc) * 64;
    const float* s = src + (size_t)e * R * C;
    unsigned short* d = dst + (size_t)e * R * C;

    const int i  = tid >> 2;          // 0..63 source row
    const int j0 = (tid & 3) * 16;    // 0,16,32,48 source col base
    #pragma unroll
    for (int k4 = 0; k4 < 4; ++k4) {
      float4 v = *(const float4*)(s + (size_t)(r0 + i) * C + c0 + j0 + k4 * 4);
      tile[i][j0 + k4 * 4 + 0] = v.x;
      tile[i][j0 + k4 * 4 + 1] = v.y;
      tile[i][j0 + k4 * 4 + 2] = v.z;
      tile[i][j0 + k4 * 4 + 3] = v.w;
    }
    __syncthreads();
    unsigned pk[8];
    #pragma unroll
    for (int k = 0; k < 8; ++k) {
      unsigned lo = f2bf(tile[j0 + 2 * k][i]);
      unsigned hi = f2bf(tile[j0 + 2 * k + 1][i]);
      pk[k] = lo | (hi << 16);
    }
    uint4 u0; u0.x = pk[0]; u0.y = pk[1]; u0.z = pk[2]; u0.w = pk[3];
    uint4 u1; u1.x = pk[4]; u1.y = pk[5]; u1.z = pk[6]; u1.w = pk[7];
    unsigned short* dp = d + (size_t)(c0 + i) * R + r0 + j0;
    *(uint4*)(dp)     = u0;
    *(uint4*)(dp + 8) = u1;
    return;
  }

  // ---- router block ---------------------------------------------------------
  float (*xs_t)[36] = (float (*)[36])smem;                   // [d=64][tok 32+pad], swizzled
  float (*ws_t)[36] = (float (*)[36])(smem + 9216);          // [d=64][e 32+pad], swizzled
  float (*S)[33]    = (float (*)[33])(smem + 18432);         // [tok=32][e 32+pad]
  float (*red)[64][16] = (float (*)[64][16])smem;            // [wave][class][16] aliases staging

  const int tok0 = bid * RT;
  const int wv   = tid >> 6;           // wave: owns d-quarter [wv*16, wv*16+16)
  const int lane = tid & 63;
  const int tr   = tid >> 3;           // staging row: token / expert 0..31
  const int i8   = tid & 7;
  const int d8   = i8 * 8;
  const int swzW = i8 << 2;            // write swizzle key
  const int tg4  = (lane & 7) * 4;     // compute: token group base
  const int eg4  = (lane >> 3) * 4;    // compute: expert group base
  const int dlo  = wv * 16;

  float acc[16];
  #pragma unroll
  for (int k = 0; k < 16; ++k) acc[k] = 0.f;

  // prologue: load chunk 0 into regs
  float4 a0, a1, b0, b1;
  {
    const float* xp = x + (size_t)(tok0 + tr) * DIM + d8;
    a0 = *(const float4*)(xp);
    a1 = *(const float4*)(xp + 4);
    const float* wp = w_sel + (size_t)tr * DIM + d8;
    b0 = *(const float4*)(wp);
    b1 = *(const float4*)(wp + 4);
  }

  for (int c = 0; c < 16; ++c) {
    const int dc = c * 64;

    // write current chunk regs -> LDS (x and w both transposed, swizzled cols)
    // + fused xbf bf16 store
    {
      const int colx = tr ^ swzW;
      xs_t[d8 + 0][colx] = a0.x; xs_t[d8 + 1][colx] = a0.y;
      xs_t[d8 + 2][colx] = a0.z; xs_t[d8 + 3][colx] = a0.w;
      xs_t[d8 + 4][colx] = a1.x; xs_t[d8 + 5][colx] = a1.y;
      xs_t[d8 + 6][colx] = a1.z; xs_t[d8 + 7][colx] = a1.w;
      ws_t[d8 + 0][colx] = b0.x; ws_t[d8 + 1][colx] = b0.y;
      ws_t[d8 + 2][colx] = b0.z; ws_t[d8 + 3][colx] = b0.w;
      ws_t[d8 + 4][colx] = b1.x; ws_t[d8 + 5][colx] = b1.y;
      ws_t[d8 + 6][colx] = b1.z; ws_t[d8 + 7][colx] = b1.w;
      uint4 u;
      u.x = (unsigned)f2bf(a0.x) | ((unsigned)f2bf(a0.y) << 16);
      u.y = (unsigned)f2bf(a0.z) | ((unsigned)f2bf(a0.w) << 16);
      u.z = (unsigned)f2bf(a1.x) | ((unsigned)f2bf(a1.y) << 16);
      u.w = (unsigned)f2bf(a1.z) | ((unsigned)f2bf(a1.w) << 16);
      *(uint4*)(xbf + (size_t)(tok0 + tr) * DIM + dc + d8) = u;
    }
    __syncthreads();

    // prefetch chunk c+1 into regs; drains under the FMA block below
    if (c < 15) {
      const float* xp = x + (size_t)(tok0 + tr) * DIM + dc + 64 + d8;
      a0 = *(const float4*)(xp);
      a1 = *(const float4*)(xp + 4);
      const float* wp = w_sel + (size_t)tr * DIM + dc + 64 + d8;
      b0 = *(const float4*)(wp);
      b1 = *(const float4*)(wp + 4);
    }

    // compute: 16 d x (4 tok x 4 exp); both reads are 8-address broadcast
    #pragma unroll
    for (int dd = 0; dd < 16; ++dd) {
      const int d  = dlo + dd;
      const int sz = (d >> 3) << 2;
      float4 xv = *(const float4*)&xs_t[d][tg4 ^ sz];
      float4 w4 = *(const float4*)&ws_t[d][eg4 ^ sz];
      acc[0]  = fmaf(w4.x, xv.x, acc[0]);  acc[1]  = fmaf(w4.x, xv.y, acc[1]);
      acc[2]  = fmaf(w4.x, xv.z, acc[2]);  acc[3]  = fmaf(w4.x, xv.w, acc[3]);
      acc[4]  = fmaf(w4.y, xv.x, acc[4]);  acc[5]  = fmaf(w4.y, xv.y, acc[5]);
      acc[6]  = fmaf(w4.y, xv.z, acc[6]);  acc[7]  = fmaf(w4.y, xv.w, acc[7]);
      acc[8]  = fmaf(w4.z, xv.x, acc[8]);  acc[9]  = fmaf(w4.z, xv.y, acc[9]);
      acc[10] = fmaf(w4.z, xv.z, acc[10]); acc[11] = fmaf(w4.z, xv.w, acc[11]);
      acc[12] = fmaf(w4.w, xv.x, acc[12]); acc[13] = fmaf(w4.w, xv.y, acc[13]);
      acc[14] = fmaf(w4.w, xv.z, acc[14]); acc[15] = fmaf(w4.w, xv.w, acc[15]);
    }
    __syncthreads();   // protect LDS before next chunk's writes
  }

  // cross-wave K reduction: red aliases staging (all staging reads done)
  #pragma unroll
  for (int ei = 0; ei < 4; ++ei) {
    float4 v; v.x = acc[ei * 4 + 0]; v.y = acc[ei * 4 + 1];
    v.z = acc[ei * 4 + 2]; v.w = acc[ei * 4 + 3];
    *(float4*)&red[wv][lane][ei * 4] = v;
  }
  __syncthreads();

  {
    const int eg2 = tid >> 5, tg2 = (tid >> 2) & 7, ei2 = tid & 3;
    const int cls = eg2 * 8 + tg2;
    float4 s4; s4.x = 0.f; s4.y = 0.f; s4.z = 0.f; s4.w = 0.f;
    #pragma unroll
    for (int w = 0; w < 4; ++w) {
      float4 v = *(const float4*)&red[w][cls][ei2 * 4];
      s4.x += v.x; s4.y += v.y; s4.z += v.z; s4.w += v.w;
    }
    S[tg2 * 4 + 0][eg2 * 4 + ei2] = s4.x;
    S[tg2 * 4 + 1][eg2 * 4 + ei2] = s4.y;
    S[tg2 * 4 + 2][eg2 * 4 + ei2] = s4.z;
    S[tg2 * 4 + 3][eg2 * 4 + ei2] = s4.w;
  }
  __syncthreads();

  if (tid < RT) {
    const int t = tid;
    float m1 = -1e30f, m2 = -1e30f;
    int i1 = 0, i2 = 0;
    for (int ee = 0; ee < NEXP; ++ee) {
      float v = S[t][ee];
      if (v > m1)      { m2 = m1; i2 = i1; m1 = v; i1 = ee; }
      else if (v > m2) { m2 = v; i2 = ee; }
    }
    const int token = tok0 + t;
    float g1 = 1.f / (1.f + __expf(-m1));
    float g2 = 1.f / (1.f + __expf(-m2));
    unsigned e1 = ((unsigned)f2bf(g1) << 16) | ((unsigned)token << 1);
    unsigned e2 = ((unsigned)f2bf(g2) << 16) | ((unsigned)token << 1) | 1u;
    int p1 = atomicAdd(&counts[i1], 1);
    if (p1 < LCAP) list[i1 * LCAP + p1] = e1;
    int p2 = atomicAdd(&counts[i2], 1);
    if (p2 < LCAP) list[i2 * LCAP + p2] = e2;
  }
}

// ---------------- Expert FFN: TT=32 tiles, LDS-bounced stores ---------------
__global__ __launch_bounds__(256, 4) void ffn_kernel(
    const unsigned short* __restrict__ xbf,
    const unsigned short* __restrict__ wk_t,   // bf16 [E][H][D]
    const unsigned short* __restrict__ wv_t,   // bf16 [E][D][H]
    float* __restrict__ out,                   // atomic mode
    unsigned short* __restrict__ cont,         // cont mode [2][NTOK][DIM] bf16
    const int* __restrict__ counts, const unsigned* __restrict__ list,
    int use_cont)
{
  const int bid = blockIdx.x;
  const int e   = bid & 31;                    // bid%8 == e%8 -> expert stays on one XCD
  const int cnt = min(counts[e], LCAP);
  const int t0  = (bid >> 5) * TT;
  if (t0 >= cnt) return;

  // xsf: A-fragments, frag (mt*4+kk)*512 + lane*8 (lane-contiguous for gload_lds)
  // st : store-bounce [32 rows][256 cols + pad], unioned with xsf (disjoint phases)
  __shared__ __align__(16) unsigned short uni[8448];   // max(2*4096, 32*264) shorts
  __shared__ unsigned short ss[TT][NH + 8];
  __shared__ int   toks[TT];
  __shared__ float gates[TT];
  unsigned short (*xsf)[4096] = (unsigned short (*)[4096])uni;
  unsigned short (*st)[264]   = (unsigned short (*)[264])uni;

  const int tid  = threadIdx.x;
  const int wave = tid >> 6;
  const int lane = tid & 63;
  const int quad = lane >> 4;
  const int l16  = lane & 15;

  const unsigned short* wkb = wk_t + (size_t)e * NH * DIM;
  const unsigned short* wvb = wv_t + (size_t)e * DIM * NH;
  const int n_tok = min(TT, cnt - t0);

  if (tid < TT) {
    int valid = tid < n_tok;
    unsigned en = valid ? list[e * LCAP + t0 + tid] : 0u;
    toks[tid]  = valid ? (int)(en & 0xffffu) : -1;
    gates[tid] = valid ? bf2f((unsigned short)(en >> 16)) : 0.f;
  }
  __syncthreads();

  // staging: waves {0,1} stage rows 0..15 (kk {0,1}/{2,3}), waves {2,3} rows 16..31
  const int smt  = wave >> 1;
  const int skk0 = (wave & 1) * 2;
  {
    int sl   = toks[smt * 16 + l16];
    int gtok = (sl < 0) ? 0 : (sl >> 1);
    const unsigned short* gsrc = xbf + (size_t)gtok * DIM + quad * 8;

    #pragma unroll
    for (int i2 = 0; i2 < 2; ++i2)
      gload_lds16(gsrc + (skk0 + i2) * 32, &xsf[0][(smt * 4 + skk0 + i2) * 512]);
    __syncthreads();

    // ---- Phase A: S = relu(X @ Wk) * gate  (M=32, N=128, K=1024)
    float4_ acc[2][2];
    #pragma unroll
    for (int mt = 0; mt < 2; ++mt)
      #pragma unroll
      for (int nt = 0; nt < 2; ++nt) acc[mt][nt] = (float4_){0.f, 0.f, 0.f, 0.f};

    for (int ci = 0; ci < 8; ++ci) {
      const int dc = ci * BK;
      if (ci < 7) {
        const int nb = (ci + 1) & 1;
        #pragma unroll
        for (int i2 = 0; i2 < 2; ++i2)
          gload_lds16(gsrc + dc + BK + (skk0 + i2) * 32,
                      &xsf[nb][(smt * 4 + skk0 + i2) * 512]);
      }
      short8 b[4][2];
      #pragma unroll
      for (int kk = 0; kk < 4; ++kk)
        #pragma unroll
        for (int nt = 0; nt < 2; ++nt)
          b[kk][nt] = *(const short8*)(wkb +
              (size_t)(wave * 32 + nt * 16 + l16) * DIM + dc + kk * 32 + quad * 8);

      const unsigned short* xb = &xsf[ci & 1][0];
      #pragma unroll
      for (int kk = 0; kk < 4; ++kk) {
        #pragma unroll
        for (int mt = 0; mt < 2; ++mt) {
          short8 a = *(const short8*)(xb + (mt * 4 + kk) * 512 + lane * 8);
          #pragma unroll
          for (int nt = 0; nt < 2; ++nt)
            acc[mt][nt] = __builtin_amdgcn_mfma_f32_16x16x32_bf16(a, b[kk][nt], acc[mt][nt], 0, 0, 0);
        }
      }
      __syncthreads();   // drains prefetch + protects buf reuse
    }

    // epilogue A: relu * gate -> bf16 scores
    #pragma unroll
    for (int mt = 0; mt < 2; ++mt)
      #pragma unroll
      for (int nt = 0; nt < 2; ++nt)
        #pragma unroll
        for (int r = 0; r < 4; ++r) {
          int row = mt * 16 + quad * 4 + r;
          float v = fmaxf(acc[mt][nt][r], 0.f) * gates[row];
          ss[row][wave * 32 + nt * 16 + l16] = f2bf(v);
        }
  }
  __syncthreads();       // xsf dead from here on -> st may alias it

  // ---- Phase B: O = S @ Wv  (M=32, N=1024, K=128)
  #pragma unroll 1
  for (int nc = 0; nc < 4; ++nc) {
    const int colbase = wave * 256 + nc * 64;
    float4_ o[2][4];
    #pragma unroll
    for (int mt = 0; mt < 2; ++mt)
      #pragma unroll
      for (int nt = 0; nt < 4; ++nt) o[mt][nt] = (float4_){0.f, 0.f, 0.f, 0.f};

    #pragma unroll
    for (int kk = 0; kk < 4; ++kk) {
      short8 bk[4];
      #pragma unroll
      for (int nt = 0; nt < 4; ++nt)
        bk[nt] = *(const short8*)(wvb +
            (size_t)(colbase + nt * 16 + l16) * NH + kk * 32 + quad * 8);
      short8 a0 = *(const short8*)&ss[l16][kk * 32 + quad * 8];
      short8 a1 = *(const short8*)&ss[16 + l16][kk * 32 + quad * 8];
      #pragma unroll
      for (int nt = 0; nt < 4; ++nt) {
        o[0][nt] = __builtin_amdgcn_mfma_f32_16x16x32_bf16(a0, bk[nt], o[0][nt], 0, 0, 0);
        o[1][nt] = __builtin_amdgcn_mfma_f32_16x16x32_bf16(a1, bk[nt], o[1][nt], 0, 0, 0);
      }
    }

    if (use_cont) {
      // bounce through LDS, then full 128B row-segment stores
      #pragma unroll
      for (int mt = 0; mt < 2; ++mt)
        #pragma unroll
        for (int nt = 0; nt < 4; ++nt)
          #pragma unroll
          for (int r = 0; r < 4; ++r)
            st[mt * 16 + quad * 4 + r][wave * 64 + nt * 16 + l16] = f2bf(o[mt][nt][r]);
      __syncthreads();
      #pragma unroll
      for (int q = 0; q < 4; ++q) {
        int idx = q * 256 + tid;
        int row = idx >> 5, seg = idx & 31;
        if (row < n_tok) {
          int sl2 = toks[row];
          size_t base = ((size_t)((sl2 & 1) * NTOK + (sl2 >> 1))) * DIM
                        + (seg >> 3) * 256 + nc * 64 + (seg & 7) * 8;
          *(short8*)&cont[base] = *(const short8*)&st[row][seg * 8];
        }
      }
      __syncthreads();   // st reused next nc
    } else {
      #pragma unroll
      for (int mt = 0; mt < 2; ++mt)
        #pragma unroll
        for (int r = 0; r < 4; ++r) {
          int row = mt * 16 + quad * 4 + r;
          if (row < n_tok) {
            size_t base = (size_t)(toks[row] >> 1) * DIM + colbase;
            #pragma unroll
            for (int nt = 0; nt < 4; ++nt)
              unsafeAtomicAdd(&out[base + nt * 16 + l16], o[mt][nt][r]);
          }
        }
    }
  }
}

// ---------------- Combine: out = cont[0] + cont[1] (bf16 -> f32) -----------
__global__ __launch_bounds__(256) void combine_kernel(
    const unsigned short* __restrict__ cont, float* __restrict__ out)
{
  size_t i = ((size_t)blockIdx.x * 256 + threadIdx.x) * 8;
  uint4 a = *(const uint4*)(cont + i);
  uint4 b = *(const uint4*)(cont + (size_t)NTOK * DIM + i);
  float4 r0, r1;
  r0.x = bf2f((unsigned short)(a.x & 0xffff)) + bf2f((unsigned short)(b.x & 0xffff));
  r0.y = bf2f((unsigned short)(a.x >> 16))    + bf2f((unsigned short)(b.x >> 16));
  r0.z = bf2f((unsigned short)(a.y & 0xffff)) + bf2f((unsigned short)(b.y & 0xffff));
  r0.w = bf2f((unsigned short)(a.y >> 16))    + bf2f((unsigned short)(b.y >> 16));
  r1.x = bf2f((unsigned short)(a.z & 0xffff)) + bf2f((unsigned short)(b.z & 0xffff));
  r1.y = bf2f((unsigned short)(a.z >> 16))    + bf2f((unsigned short)(b.z >> 16));
  r1.z = bf2f((unsigned short)(a.w & 0xffff)) + bf2f((unsigned short)(b.w & 0xffff));
  r1.w = bf2f((unsigned short)(a.w >> 16))    + bf2f((unsigned short)(b.w >> 16));
  *(float4*)(out + i) = r0;
  *(float4*)(out + i + 4) = r1;
}

extern "C" void kernel_launch(void* const* d_in, const int* in_sizes, int n_in,
                              void* d_out, int out_size, void* d_ws, size_t ws_size,
                              hipStream_t stream) {
  (void)in_sizes; (void)n_in;
  const float* x        = (const float*)d_in[0];
  const float* w_sel    = (const float*)d_in[1];
  const float* w_keys   = (const float*)d_in[2];
  const float* w_values = (const float*)d_in[3];
  float* out = (float*)d_out;

  // workspace layout
  char* ws = (char*)d_ws;
  size_t off = 0;
  int*            counts = (int*)(ws + off);            off += 4096;
  unsigned*       list   = (unsigned*)(ws + off);       off += (size_t)NEXP * LCAP * 4;      // 128 KB
  unsigned short* wk_t   = (unsigned short*)(ws + off); off += (size_t)NEXP * NH * DIM * 2;  // 8 MB
  unsigned short* wv_t   = (unsigned short*)(ws + off); off += (size_t)NEXP * NH * DIM * 2;  // 8 MB
  unsigned short* xbf    = (unsigned short*)(ws + off); off += (size_t)NTOK * DIM * 2;       // 16 MB
  unsigned short* cont   = (unsigned short*)(ws + off);
  size_t need_full = off + (size_t)2 * NTOK * DIM * 2;  // + 32 MB
  const int use_cont = (ws_size >= need_full) ? 1 : 0;

  hipMemsetAsync(counts, 0, NEXP * sizeof(int), stream);

  prep_router_kernel<<<NRB + 2048, 256, 0, stream>>>(x, w_sel, w_keys, w_values,
                                                     xbf, wk_t, wv_t, counts, list);

  if (!use_cont)
    hipMemsetAsync(out, 0, (size_t)out_size * sizeof(float), stream);

  ffn_kernel<<<NEXP * NSLOT, 256, 0, stream>>>(xbf, wk_t, wv_t, out, cont,
                                               counts, list, use_cont);

  if (use_cont)
    combine_kernel<<<NTOK * DIM / (256 * 8), 256, 0, stream>>>(cont, out);
}